// Round 5
// baseline (447.059 us; speedup 1.0000x reference)
//
#include <hip/hip_runtime.h>

// Problem constants
#define BN   8
#define CC   256
#define HH   64
#define WW   64
#define GG   8
#define CG   32
#define KKK  9
#define OO   256
#define HW   (HH*WW)
#define NPAD 224
#define NOUT 216

typedef __attribute__((ext_vector_type(8))) _Float16 half8;
typedef __attribute__((ext_vector_type(4))) _Float16 half4;
typedef __attribute__((ext_vector_type(4))) float f32x4;

union U4H8 { uint4 u; half8 h; };

// ---------------------------------------------------------------------------
// K0a: repack w_out [O][C][3][3] -> wt3 f16 [g*9+kk][o 256][cg 32]
// ---------------------------------------------------------------------------
__global__ void repack_w(const float* __restrict__ w_out, _Float16* __restrict__ wt3) {
    int idx = blockIdx.x * 256 + threadIdx.x;
    if (idx >= GG * KKK * CG * OO) return;
    int cg = idx & 31;
    int o  = (idx >> 5) & 255;
    int s  = idx >> 13;
    int kk = s % 9;
    int g  = s / 9;
    wt3[idx] = (_Float16)w_out[o * 2304 + (g * 32 + cg) * 9 + kk];
}

// ---------------------------------------------------------------------------
// K0b: repack conv weights -> wt_conv f16 [tap][oc 224][c 256]; also bias[224]
// ---------------------------------------------------------------------------
__global__ void repack_conv(const float* __restrict__ w_off, const float* __restrict__ b_off,
                            const float* __restrict__ w_attn, const float* __restrict__ b_attn,
                            _Float16* __restrict__ wt_conv, float* __restrict__ bias_c) {
    int idx = blockIdx.x * 256 + threadIdx.x;
    if (idx >= 9 * NPAD * 256) return;
    int c = idx & 255;
    int r = idx >> 8;
    int n = r % NPAD;
    int tap = r / NPAD;
    float v = 0.f;
    if (n < 144)      v = w_off[(n * 256 + c) * 9 + tap];
    else if (n < 216) v = w_attn[((n - 144) * 256 + c) * 9 + tap];
    wt_conv[(tap * NPAD + n) * 256 + c] = (_Float16)v;
    if (idx < NPAD) {
        float bv = 0.f;
        if (idx < 144)      bv = b_off[idx];
        else if (idx < 216) bv = b_attn[idx - 144];
        bias_c[idx] = bv;
    }
}

// ---------------------------------------------------------------------------
// K0c: repack x f32 NCHW -> x_h f16 NHWC [b][y][x][c]
// ---------------------------------------------------------------------------
__global__ __launch_bounds__(256) void repack_x(const float* __restrict__ x,
                                                _Float16* __restrict__ x_h) {
    __shared__ _Float16 T[64][264];
    const int bid = blockIdx.x;
    const int b = bid & 7, h = bid >> 3;
    const int t = threadIdx.x;   // = channel
    const float* src = x + (((long)(b * 256 + t)) << 12) + h * 64;
    #pragma unroll
    for (int i = 0; i < 16; ++i) {
        float4 f = ((const float4*)src)[i];
        T[i * 4 + 0][t] = (_Float16)f.x;
        T[i * 4 + 1][t] = (_Float16)f.y;
        T[i * 4 + 2][t] = (_Float16)f.z;
        T[i * 4 + 3][t] = (_Float16)f.w;
    }
    __syncthreads();
    _Float16* dst = x_h + (((long)(b * 4096 + h * 64)) << 8);
    #pragma unroll
    for (int it = 0; it < 8; ++it) {
        int idx = it * 256 + t;
        int px = idx >> 5, ch = idx & 31;
        uint4 v = *(const uint4*)&T[px][ch * 8];
        *(uint4*)(dst + px * 256 + ch * 8) = v;
    }
}

// ---------------------------------------------------------------------------
// K1: implicit-GEMM conv via f16 MFMA, 2-stage supersteps (64-ch chunks).
// Block = (b,h) XCD-swizzled, 512 thr. M=64 px x N=224 oc.
// 36 supersteps = (tap 0..8) x (64-ch chunk 0..3); each stages two 32-ch
// sub-tiles, 14 MFMA per wave per barrier pair.
// ---------------------------------------------------------------------------
__global__ __launch_bounds__(512, 4) void conv_mfma(
    const _Float16* __restrict__ x_h, const _Float16* __restrict__ wt_conv,
    const float* __restrict__ bias_c, float* __restrict__ conv_buf) {
    __shared__ _Float16 A2[2][64][40];   // 10 KB
    __shared__ _Float16 B2[2][NPAD][40]; // 35 KB

    const int bid = blockIdx.x;
    const int b = bid & 7, h = bid >> 3;
    const int t = threadIdx.x;
    const int lane = t & 63;
    const int wv = t >> 6;
    const int mt = wv & 3;          // M-tile
    const int nh = wv >> 2;         // N half: tiles nh*7..nh*7+6
    const int sub = t >> 8;         // which 32-ch sub-tile this thread stages
    const int px  = (t & 255) >> 2; // staging pixel
    const int cq  = t & 3;          // channel quad (8 ch)
    const bool has4 = (t < 256);    // 4th B load valid

    f32x4 acc[7];
    #pragma unroll
    for (int i = 0; i < 7; ++i) acc[i] = (f32x4){0.f, 0.f, 0.f, 0.f};

    const _Float16* xb = x_h + ((long)b << 20) + sub * 32 + cq * 8;

    // pipeline regs
    uint4 aR; bool vA;
    uint4 p[4];

    // ---- preamble: superstep 0 (tap 0: ti=0,tj=0; c64=0) ----
    {
        int y = h - 1, xc = px - 1;
        vA = ((unsigned)y < 64u) && ((unsigned)xc < 64u);
        int yc = min(max(y, 0), 63), xcc = min(max(xc, 0), 63);
        aR = *(const uint4*)(xb + ((long)(yc * 64 + xcc)) * 256);
        const _Float16* base = wt_conv;
        #pragma unroll
        for (int i2 = 0; i2 < 4; ++i2) {
            int e = i2 * 512 + t;
            if (i2 < 3 || has4) {
                int n = e >> 3, r = e & 7, sb = r >> 2, part = r & 3;
                p[i2] = *(const uint4*)(base + n * 256 + sb * 32 + part * 8);
            }
        }
    }

    for (int ss = 0; ss < 36; ++ss) {
        // ---- LDS write phase ----
        {
            #pragma unroll
            for (int i2 = 0; i2 < 4; ++i2) {
                int e = i2 * 512 + t;
                if (i2 < 3 || has4) {
                    int n = e >> 3, r = e & 7, sb = r >> 2, part = r & 3;
                    *(uint4*)&B2[sb][n][part * 8] = p[i2];
                }
            }
            uint4 az = vA ? aR : make_uint4(0u, 0u, 0u, 0u);
            *(uint4*)&A2[sub][px][cq * 8] = az;
        }
        // ---- issue next-superstep loads ----
        if (ss < 35) {
            int sn = ss + 1;
            int tap = sn >> 2, c64 = sn & 3;
            int ti = tap / 3, tj = tap % 3;
            int y = h + ti - 1, xc = px + tj - 1;
            vA = ((unsigned)y < 64u) && ((unsigned)xc < 64u);
            int yc = min(max(y, 0), 63), xcc = min(max(xc, 0), 63);
            aR = *(const uint4*)(xb + ((long)(yc * 64 + xcc)) * 256 + c64 * 64);
            const _Float16* base = wt_conv + (long)tap * NPAD * 256 + c64 * 64;
            #pragma unroll
            for (int i2 = 0; i2 < 4; ++i2) {
                int e = i2 * 512 + t;
                if (i2 < 3 || has4) {
                    int n = e >> 3, r = e & 7, sb = r >> 2, part = r & 3;
                    p[i2] = *(const uint4*)(base + n * 256 + sb * 32 + part * 8);
                }
            }
        }
        __syncthreads();

        // ---- MFMA: 2 sub-tiles x (1 M x 7 N) per wave ----
        const int k0 = (lane >> 4) * 8;
        #pragma unroll
        for (int s2 = 0; s2 < 2; ++s2) {
            half8 a = *(const half8*)&A2[s2][mt * 16 + (lane & 15)][k0];
            #pragma unroll
            for (int j = 0; j < 7; ++j) {
                half8 bf = *(const half8*)&B2[s2][(nh * 7 + j) * 16 + (lane & 15)][k0];
                acc[j] = __builtin_amdgcn_mfma_f32_16x16x32_f16(a, bf, acc[j], 0, 0, 0);
            }
        }
        __syncthreads();
    }

    // ---- epilogue ----
    const int colb = mt * 16 + ((lane >> 4) * 4);
    #pragma unroll
    for (int i = 0; i < 7; ++i) {
        int oc = (nh * 7 + i) * 16 + (lane & 15);
        if (oc < NOUT) {
            float bb = bias_c[oc];
            float4 v = make_float4(acc[i][0] + bb, acc[i][1] + bb,
                                   acc[i][2] + bb, acc[i][3] + bb);
            *(float4*)&conv_buf[((long)b * NOUT + oc) * HW + h * WW + colb] = v;
        }
    }
}

// ---------------------------------------------------------------------------
// K2: in-place softmax over the 9 kernel taps
// ---------------------------------------------------------------------------
__global__ void softmax9(float* __restrict__ conv_buf) {
    int idx = blockIdx.x * 256 + threadIdx.x;
    if (idx >= BN * GG * HW) return;
    int hw = idx & (HW - 1);
    int r = idx >> 12;
    int g = r & 7;
    int b = r >> 3;
    float* p = conv_buf + ((long)b * NOUT + 144 + g * KKK) * HW + hw;
    float v[9];
    float m = -1e30f;
    #pragma unroll
    for (int k = 0; k < 9; ++k) { v[k] = p[k * HW]; m = fmaxf(m, v[k]); }
    float s = 0.f;
    #pragma unroll
    for (int k = 0; k < 9; ++k) { v[k] = __expf(v[k] - m); s += v[k]; }
    float inv = 1.f / s;
    #pragma unroll
    for (int k = 0; k < 9; ++k) p[k * HW] = v[k] * inv;
}

__device__ __forceinline__ void calc_coords(int h, int px, int ki, int kj,
    float dy, float dx, float av,
    int& i00, int& i01, int& i10, int& i11,
    float& u00, float& u01, float& u10, float& u11) {
    float py  = (float)(h - 1 + ki) + dy;
    float pxf = (float)(px - 1 + kj) + dx;
    float y0f = floorf(py), x0f = floorf(pxf);
    int y0 = (int)y0f, x0 = (int)x0f;
    float wy1 = py - y0f, wx1 = pxf - x0f;
    float wy0 = 1.f - wy1, wx0 = 1.f - wx1;
    int y1 = y0 + 1, x1 = x0 + 1;
    float m00 = (((unsigned)y0 < 64u) && ((unsigned)x0 < 64u)) ? av : 0.f;
    float m01 = (((unsigned)y0 < 64u) && ((unsigned)x1 < 64u)) ? av : 0.f;
    float m10 = (((unsigned)y1 < 64u) && ((unsigned)x0 < 64u)) ? av : 0.f;
    float m11 = (((unsigned)y1 < 64u) && ((unsigned)x1 < 64u)) ? av : 0.f;
    int cy0 = min(max(y0, 0), 63), cy1 = min(max(y1, 0), 63);
    int cx0 = min(max(x0, 0), 63), cx1 = min(max(x1, 0), 63);
    u00 = wy0 * wx0 * m00; u01 = wy0 * wx1 * m01;
    u10 = wy1 * wx0 * m10; u11 = wy1 * wx1 * m11;
    i00 = cy0 * 64 + cx0; i01 = cy0 * 64 + cx1;
    i10 = cy1 * 64 + cx0; i11 = cy1 * 64 + cx1;
}

// ---------------------------------------------------------------------------
// K3: fused bilinear sampling + modulation + MFMA contraction,
// 2-stage supersteps. Block = (b,h) XCD-swizzled, 512 thr.
// Thread t: sub=t>>8 picks stage parity; 4 threads/px, 8 ch each (uint4
// gathers from f16 NHWC). 36 barrier pairs, 16 MFMA/wave each.
// ---------------------------------------------------------------------------
__global__ __launch_bounds__(512, 4) void sample_gemm_mfma(
    const _Float16* __restrict__ x_h, const float* __restrict__ conv_buf,
    const _Float16* __restrict__ wt3,
    const float* __restrict__ b_out, float* __restrict__ out) {
    __shared__ _Float16 A2[2][64][40];   // 10 KB
    __shared__ _Float16 B2[2][OO][40];   // 40 KB

    const int bid = blockIdx.x;
    const int b = bid & 7, h = bid >> 3;
    const int t = threadIdx.x;
    const int lane = t & 63;
    const int wv = t >> 6;
    const int mh = wv & 1;
    const int nh = wv >> 1;
    const int sub = t >> 8;          // stage parity staged by this thread
    const int px  = (t & 255) >> 2;  // gather pixel
    const int cq  = t & 3;           // channel quad (8 ch)

    f32x4 acc[2][4];
    #pragma unroll
    for (int i = 0; i < 2; ++i)
        #pragma unroll
        for (int j = 0; j < 4; ++j) acc[i][j] = (f32x4){0.f, 0.f, 0.f, 0.f};

    const float* cb = conv_buf + (long)b * NOUT * HW + h * WW + px;
    const _Float16* xbase = x_h + ((long)b << 20) + cq * 8;

    // pipeline state
    uint4 q00, q01, q10, q11;
    float u00, u01, u10, u11;
    uint4 p[4];
    float dyN, dxN, avN;

    // ---- preamble: superstep 0 (stages sub=0/1; g=0) ----
    {
        int s = sub;
        float dy = cb[(s * 2) * HW], dx = cb[(s * 2 + 1) * HW], av = cb[(144 + s) * HW];
        int i00, i01, i10, i11;
        calc_coords(h, px, s / 3, s % 3, dy, dx, av, i00, i01, i10, i11,
                    u00, u01, u10, u11);
        q00 = *(const uint4*)(xbase + (long)i00 * 256);
        q01 = *(const uint4*)(xbase + (long)i01 * 256);
        q10 = *(const uint4*)(xbase + (long)i10 * 256);
        q11 = *(const uint4*)(xbase + (long)i11 * 256);
        #pragma unroll
        for (int i2 = 0; i2 < 4; ++i2) {
            int e = i2 * 512 + t;
            int sb = e >> 10, r = e & 1023, n = r >> 2, part = r & 3;
            p[i2] = *(const uint4*)(wt3 + (long)sb * 8192 + n * 32 + part * 8);
        }
        int sN = 2 + sub;
        dyN = cb[(sN * 2) * HW]; dxN = cb[(sN * 2 + 1) * HW]; avN = cb[(144 + sN) * HW];
    }

    for (int ss = 0; ss < 36; ++ss) {
        // ---- LDS write phase ----
        {
            #pragma unroll
            for (int i2 = 0; i2 < 4; ++i2) {
                int e = i2 * 512 + t;
                int sb = e >> 10, r = e & 1023, n = r >> 2, part = r & 3;
                *(uint4*)&B2[sb][n][part * 8] = p[i2];
            }
            U4H8 a00, a01, a10, a11;
            a00.u = q00; a01.u = q01; a10.u = q10; a11.u = q11;
            half8 rr;
            #pragma unroll
            for (int c = 0; c < 8; ++c) {
                float v = u00 * (float)a00.h[c] + u01 * (float)a01.h[c]
                        + u10 * (float)a10.h[c] + u11 * (float)a11.h[c];
                rr[c] = (_Float16)v;
            }
            *(half8*)&A2[sub][px][cq * 8] = rr;
        }
        // ---- issue next-superstep loads ----
        if (ss < 35) {
            int sN = 2 * (ss + 1) + sub;
            int g = sN / 9, kk = sN % 9;
            int i00, i01, i10, i11;
            calc_coords(h, px, kk / 3, kk % 3, dyN, dxN, avN, i00, i01, i10, i11,
                        u00, u01, u10, u11);
            const _Float16* xg = xbase + g * 32;
            q00 = *(const uint4*)(xg + (long)i00 * 256);
            q01 = *(const uint4*)(xg + (long)i01 * 256);
            q10 = *(const uint4*)(xg + (long)i10 * 256);
            q11 = *(const uint4*)(xg + (long)i11 * 256);
            const _Float16* ws = wt3 + (long)(2 * (ss + 1)) * 8192;
            #pragma unroll
            for (int i2 = 0; i2 < 4; ++i2) {
                int e = i2 * 512 + t;
                int sb = e >> 10, r = e & 1023, n = r >> 2, part = r & 3;
                p[i2] = *(const uint4*)(ws + (long)sb * 8192 + n * 32 + part * 8);
            }
            int sF = 2 * min(ss + 2, 35) + sub;
            dyN = cb[(sF * 2) * HW]; dxN = cb[(sF * 2 + 1) * HW]; avN = cb[(144 + sF) * HW];
        }
        __syncthreads();

        // ---- MFMA: 2 sub-stages x (2 M x 4 N) per wave ----
        const int k0 = (lane >> 4) * 8;
        #pragma unroll
        for (int s2 = 0; s2 < 2; ++s2) {
            half8 a0 = *(const half8*)&A2[s2][mh * 32 + (lane & 15)][k0];
            half8 a1 = *(const half8*)&A2[s2][mh * 32 + 16 + (lane & 15)][k0];
            #pragma unroll
            for (int j = 0; j < 4; ++j) {
                half8 bf = *(const half8*)&B2[s2][(nh * 4 + j) * 16 + (lane & 15)][k0];
                acc[0][j] = __builtin_amdgcn_mfma_f32_16x16x32_f16(a0, bf, acc[0][j], 0, 0, 0);
                acc[1][j] = __builtin_amdgcn_mfma_f32_16x16x32_f16(a1, bf, acc[1][j], 0, 0, 0);
            }
        }
        __syncthreads();
    }

    // ---- epilogue ----
    #pragma unroll
    for (int mi = 0; mi < 2; ++mi) {
        int px0 = mh * 32 + mi * 16 + (lane >> 4) * 4;
        #pragma unroll
        for (int j = 0; j < 4; ++j) {
            int oc = (nh * 4 + j) * 16 + (lane & 15);
            float bb = b_out[oc];
            float4 v = make_float4(acc[mi][j][0] + bb, acc[mi][j][1] + bb,
                                   acc[mi][j][2] + bb, acc[mi][j][3] + bb);
            *(float4*)&out[((long)b * OO + oc) * HW + h * WW + px0] = v;
        }
    }
}

// ---------------------------------------------------------------------------
extern "C" void kernel_launch(void* const* d_in, const int* in_sizes, int n_in,
                              void* d_out, int out_size, void* d_ws, size_t ws_size,
                              hipStream_t stream) {
    const float* x      = (const float*)d_in[0];
    const float* w_off  = (const float*)d_in[1];
    const float* b_off  = (const float*)d_in[2];
    const float* w_attn = (const float*)d_in[3];
    const float* b_attn = (const float*)d_in[4];
    const float* w_out  = (const float*)d_in[5];
    const float* b_out  = (const float*)d_in[6];
    float* out = (float*)d_out;

    _Float16* x_h     = (_Float16*)d_ws;                    // 8,388,608 halves
    float* conv_buf   = (float*)(x_h + 8388608);            // 7,077,888 floats
    _Float16* wt3     = (_Float16*)(conv_buf + 7077888);    // 589,824 halves
    _Float16* wt_conv = wt3 + 589824;                       // 516,096 halves
    float* bias_c     = (float*)(wt_conv + 516096);         // 224 floats

    repack_w<<<dim3((589824 + 255) / 256), dim3(256), 0, stream>>>(w_out, wt3);
    repack_conv<<<dim3((9 * NPAD * 256 + 255) / 256), dim3(256), 0, stream>>>(
        w_off, b_off, w_attn, b_attn, wt_conv, bias_c);
    repack_x<<<dim3(512), dim3(256), 0, stream>>>(x, x_h);

    conv_mfma<<<dim3(512), dim3(512), 0, stream>>>(x_h, wt_conv, bias_c, conv_buf);

    softmax9<<<dim3((BN * GG * HW) / 256), dim3(256), 0, stream>>>(conv_buf);

    sample_gemm_mfma<<<dim3(512), dim3(512), 0, stream>>>(
        x_h, conv_buf, wt3, b_out, out);
}

// Round 6
// 265.622 us; speedup vs baseline: 1.6831x; 1.6831x over previous
//
#include <hip/hip_runtime.h>

// Problem constants
#define BN   8
#define CC   256
#define HH   64
#define WW   64
#define GG   8
#define CG   32
#define KKK  9
#define OO   256
#define HW   (HH*WW)
#define NPAD 224
#define NOUT 216

typedef __attribute__((ext_vector_type(8))) _Float16 half8;
typedef __attribute__((ext_vector_type(4))) _Float16 half4;
typedef __attribute__((ext_vector_type(4))) float f32x4;

union U4H8 { uint4 u; half8 h; };

// ---------------------------------------------------------------------------
// K0a: repack w_out [O][C][3][3] -> wt3 f16 [g*9+kk][o 256][cg 32]
// ---------------------------------------------------------------------------
__global__ void repack_w(const float* __restrict__ w_out, _Float16* __restrict__ wt3) {
    int idx = blockIdx.x * 256 + threadIdx.x;
    if (idx >= GG * KKK * CG * OO) return;
    int cg = idx & 31;
    int o  = (idx >> 5) & 255;
    int s  = idx >> 13;
    int kk = s % 9;
    int g  = s / 9;
    wt3[idx] = (_Float16)w_out[o * 2304 + (g * 32 + cg) * 9 + kk];
}

// ---------------------------------------------------------------------------
// K0b: repack conv weights -> wt_conv f16 [tap][oc 224][c 256]; also bias[224]
// ---------------------------------------------------------------------------
__global__ void repack_conv(const float* __restrict__ w_off, const float* __restrict__ b_off,
                            const float* __restrict__ w_attn, const float* __restrict__ b_attn,
                            _Float16* __restrict__ wt_conv, float* __restrict__ bias_c) {
    int idx = blockIdx.x * 256 + threadIdx.x;
    if (idx >= 9 * NPAD * 256) return;
    int c = idx & 255;
    int r = idx >> 8;
    int n = r % NPAD;
    int tap = r / NPAD;
    float v = 0.f;
    if (n < 144)      v = w_off[(n * 256 + c) * 9 + tap];
    else if (n < 216) v = w_attn[((n - 144) * 256 + c) * 9 + tap];
    wt_conv[(tap * NPAD + n) * 256 + c] = (_Float16)v;
    if (idx < NPAD) {
        float bv = 0.f;
        if (idx < 144)      bv = b_off[idx];
        else if (idx < 216) bv = b_attn[idx - 144];
        bias_c[idx] = bv;
    }
}

// ---------------------------------------------------------------------------
// K0c: repack x f32 NCHW -> x_h f16 NHWC [b][y][x][c]
// ---------------------------------------------------------------------------
__global__ __launch_bounds__(256) void repack_x(const float* __restrict__ x,
                                                _Float16* __restrict__ x_h) {
    __shared__ _Float16 T[64][264];
    const int bid = blockIdx.x;
    const int b = bid & 7, h = bid >> 3;
    const int t = threadIdx.x;   // = channel
    const float* src = x + (((long)(b * 256 + t)) << 12) + h * 64;
    #pragma unroll
    for (int i = 0; i < 16; ++i) {
        float4 f = ((const float4*)src)[i];
        T[i * 4 + 0][t] = (_Float16)f.x;
        T[i * 4 + 1][t] = (_Float16)f.y;
        T[i * 4 + 2][t] = (_Float16)f.z;
        T[i * 4 + 3][t] = (_Float16)f.w;
    }
    __syncthreads();
    _Float16* dst = x_h + (((long)(b * 4096 + h * 64)) << 8);
    #pragma unroll
    for (int it = 0; it < 8; ++it) {
        int idx = it * 256 + t;
        int px = idx >> 5, ch = idx & 31;
        uint4 v = *(const uint4*)&T[px][ch * 8];
        *(uint4*)(dst + px * 256 + ch * 8) = v;
    }
}

// ---------------------------------------------------------------------------
// K1: implicit-GEMM conv via f16 MFMA.
// Block = 256 thr (4 waves), M=64 px x N=112 oc (half); grid 1024 = (b,h,half),
// b = bid&7 pins batch to XCD. 72 stages (tap x 32-ch chunk), 1-stage register
// prefetch, 7 MFMA per wave per stage.
// ---------------------------------------------------------------------------
__global__ __launch_bounds__(256, 4) void conv_mfma(
    const _Float16* __restrict__ x_h, const _Float16* __restrict__ wt_conv,
    const float* __restrict__ bias_c, float* __restrict__ conv_buf) {
    __shared__ _Float16 Ald[64][40];    // 5 KB
    __shared__ _Float16 Bld[112][40];   // 8.75 KB

    const int bid = blockIdx.x;
    const int b = bid & 7, h = (bid >> 3) & 63, half = bid >> 9;
    const int t = threadIdx.x;
    const int lane = t & 63;
    const int mt = t >> 6;          // wave = M-tile
    const int px = t >> 2, cq = t & 3;
    const int bn = t >> 2, bp = t & 3;      // B: row, part
    const bool hasB2 = (t < 192);           // rows 64..111

    f32x4 acc[7];
    #pragma unroll
    for (int i = 0; i < 7; ++i) acc[i] = (f32x4){0.f, 0.f, 0.f, 0.f};

    const _Float16* xb = x_h + ((long)b << 20) + cq * 8;
    const _Float16* wb = wt_conv + (long)(half * 112) * 256;

    uint4 aR; bool vA;
    uint4 p0, p1;

    // ---- preamble: stage 0 (tap 0: y=h-1, xc=px-1; chunk 0) ----
    {
        int y = h - 1, xc = px - 1;
        vA = ((unsigned)y < 64u) && ((unsigned)xc < 64u);
        int yc = min(max(y, 0), 63), xcc = min(max(xc, 0), 63);
        aR = *(const uint4*)(xb + ((long)(yc * 64 + xcc)) * 256);
        p0 = *(const uint4*)(wb + bn * 256 + bp * 8);
        if (hasB2) p1 = *(const uint4*)(wb + (bn + 64) * 256 + bp * 8);
    }

    for (int ss = 0; ss < 72; ++ss) {
        // ---- LDS write from prefetched regs ----
        {
            uint4 az = vA ? aR : make_uint4(0u, 0u, 0u, 0u);
            *(uint4*)&Ald[px][cq * 8] = az;
            *(uint4*)&Bld[bn][bp * 8] = p0;
            if (hasB2) *(uint4*)&Bld[bn + 64][bp * 8] = p1;
        }
        // ---- issue next-stage loads ----
        if (ss < 71) {
            int sn = ss + 1;
            int tap = sn >> 3, cc = sn & 7;
            int ti = tap / 3, tj = tap % 3;
            int y = h + ti - 1, xc = px + tj - 1;
            vA = ((unsigned)y < 64u) && ((unsigned)xc < 64u);
            int yc = min(max(y, 0), 63), xcc = min(max(xc, 0), 63);
            aR = *(const uint4*)(xb + ((long)(yc * 64 + xcc)) * 256 + cc * 32);
            const _Float16* ws = wb + (long)tap * NPAD * 256 + cc * 32;
            p0 = *(const uint4*)(ws + bn * 256 + bp * 8);
            if (hasB2) p1 = *(const uint4*)(ws + (bn + 64) * 256 + bp * 8);
        }
        __syncthreads();

        // ---- MFMA: 1 M-tile x 7 N-tiles per wave ----
        const int k0 = (lane >> 4) * 8;
        half8 a = *(const half8*)&Ald[mt * 16 + (lane & 15)][k0];
        #pragma unroll
        for (int j = 0; j < 7; ++j) {
            half8 bf = *(const half8*)&Bld[j * 16 + (lane & 15)][k0];
            acc[j] = __builtin_amdgcn_mfma_f32_16x16x32_f16(a, bf, acc[j], 0, 0, 0);
        }
        __syncthreads();
    }

    // ---- epilogue ----
    const int colb = mt * 16 + ((lane >> 4) * 4);
    #pragma unroll
    for (int i = 0; i < 7; ++i) {
        int oc = half * 112 + i * 16 + (lane & 15);
        if (oc < NOUT) {
            float bb = bias_c[oc];
            float4 v = make_float4(acc[i][0] + bb, acc[i][1] + bb,
                                   acc[i][2] + bb, acc[i][3] + bb);
            *(float4*)&conv_buf[((long)b * NOUT + oc) * HW + h * WW + colb] = v;
        }
    }
}

// ---------------------------------------------------------------------------
// coords without attn: masked bilinear weights + clamped corner indices
// ---------------------------------------------------------------------------
__device__ __forceinline__ void calc_coords(int h, int px, int ki, int kj,
    float dy, float dx,
    int& i00, int& i01, int& i10, int& i11,
    float& u00, float& u01, float& u10, float& u11) {
    float py  = (float)(h - 1 + ki) + dy;
    float pxf = (float)(px - 1 + kj) + dx;
    float y0f = floorf(py), x0f = floorf(pxf);
    int y0 = (int)y0f, x0 = (int)x0f;
    float wy1 = py - y0f, wx1 = pxf - x0f;
    float wy0 = 1.f - wy1, wx0 = 1.f - wx1;
    int y1 = y0 + 1, x1 = x0 + 1;
    float m00 = (((unsigned)y0 < 64u) && ((unsigned)x0 < 64u)) ? 1.f : 0.f;
    float m01 = (((unsigned)y0 < 64u) && ((unsigned)x1 < 64u)) ? 1.f : 0.f;
    float m10 = (((unsigned)y1 < 64u) && ((unsigned)x0 < 64u)) ? 1.f : 0.f;
    float m11 = (((unsigned)y1 < 64u) && ((unsigned)x1 < 64u)) ? 1.f : 0.f;
    int cy0 = min(max(y0, 0), 63), cy1 = min(max(y1, 0), 63);
    int cx0 = min(max(x0, 0), 63), cx1 = min(max(x1, 0), 63);
    u00 = wy0 * wx0 * m00; u01 = wy0 * wx1 * m01;
    u10 = wy1 * wx0 * m10; u11 = wy1 * wx1 * m11;
    i00 = cy0 * 64 + cx0; i01 = cy0 * 64 + cx1;
    i10 = cy1 * 64 + cx0; i11 = cy1 * 64 + cx1;
}

// ---------------------------------------------------------------------------
// K3: fused softmax + bilinear sampling + modulation + MFMA contraction.
// Block = 256 thr (4 waves), M=64 px x N=128 oc (half); grid 1024 = (b,h,half).
// Softmax over 9 taps computed once into LDS in the preamble.
// 72 (g,kk) stages; 4 thr/px gather 8 ch via uint4; pk-f16 weighted blend.
// ---------------------------------------------------------------------------
__global__ __launch_bounds__(256, 4) void sample_gemm_mfma(
    const _Float16* __restrict__ x_h, const float* __restrict__ conv_buf,
    const _Float16* __restrict__ wt3,
    const float* __restrict__ b_out, float* __restrict__ out) {
    __shared__ _Float16 Ald[64][40];    // 5 KB
    __shared__ _Float16 Bld[128][40];   // 10 KB
    __shared__ float attnL[72 * 64];    // 18 KB

    const int bid = blockIdx.x;
    const int b = bid & 7, h = (bid >> 3) & 63, half = bid >> 9;
    const int t = threadIdx.x;
    const int lane = t & 63;
    const int wv = t >> 6;
    const int mh = wv & 1;          // M-tiles mh*32..
    const int nh = wv >> 1;         // N-tiles nh*4..nh*4+3 (of 8)
    const int px = t >> 2, cq = t & 3;
    const int bn = t >> 2, bp = t & 3;

    f32x4 acc[2][4];
    #pragma unroll
    for (int i = 0; i < 2; ++i)
        #pragma unroll
        for (int j = 0; j < 4; ++j) acc[i][j] = (f32x4){0.f, 0.f, 0.f, 0.f};

    const float* cbase = conv_buf + (long)b * NOUT * HW + h * WW;
    const _Float16* xbase = x_h + ((long)b << 20) + cq * 8;

    // ---- preamble 1: softmax over 9 taps -> attnL[s][px] ----
    #pragma unroll
    for (int i = 0; i < 2; ++i) {
        int pi = t + i * 256;            // 0..511 = (g 0..7, px 0..63)
        int ppx = pi & 63, g = pi >> 6;
        const float* ap = cbase + (long)(144 + g * 9) * HW + ppx;
        float v[9];
        float m = -1e30f;
        #pragma unroll
        for (int k = 0; k < 9; ++k) { v[k] = ap[k * HW]; m = fmaxf(m, v[k]); }
        float ssum = 0.f;
        #pragma unroll
        for (int k = 0; k < 9; ++k) { v[k] = __expf(v[k] - m); ssum += v[k]; }
        float inv = 1.f / ssum;
        #pragma unroll
        for (int k = 0; k < 9; ++k) attnL[(g * 9 + k) * 64 + ppx] = v[k] * inv;
    }

    // ---- preamble 2: prefetch stage 0 ----
    uint4 q00, q01, q10, q11;
    float u00, u01, u10, u11;
    uint4 p0, p1;
    float dyN, dxN;
    {
        float dy = cbase[px], dx = cbase[HW + px];
        int i00, i01, i10, i11;
        calc_coords(h, px, 0, 0, dy, dx, i00, i01, i10, i11, u00, u01, u10, u11);
        q00 = *(const uint4*)(xbase + (long)i00 * 256);
        q01 = *(const uint4*)(xbase + (long)i01 * 256);
        q10 = *(const uint4*)(xbase + (long)i10 * 256);
        q11 = *(const uint4*)(xbase + (long)i11 * 256);
        const _Float16* ws = wt3 + (long)half * 4096;
        p0 = *(const uint4*)(ws + bn * 32 + bp * 8);
        p1 = *(const uint4*)(ws + (bn + 64) * 32 + bp * 8);
        dyN = cbase[2 * HW + px]; dxN = cbase[3 * HW + px];
    }
    __syncthreads();   // attnL ready

    for (int ss = 0; ss < 72; ++ss) {
        // ---- LDS write from prefetched regs ----
        {
            *(uint4*)&Bld[bn][bp * 8] = p0;
            *(uint4*)&Bld[bn + 64][bp * 8] = p1;
            float av = attnL[ss * 64 + px];
            U4H8 a00, a01, a10, a11;
            a00.u = q00; a01.u = q01; a10.u = q10; a11.u = q11;
            half8 rr = a00.h * (_Float16)u00 + a01.h * (_Float16)u01
                     + a10.h * (_Float16)u10 + a11.h * (_Float16)u11;
            rr = rr * (_Float16)av;
            *(half8*)&Ald[px][cq * 8] = rr;
        }
        // ---- issue next-stage loads ----
        if (ss < 71) {
            int sn = ss + 1;
            int g = sn / 9, kk = sn % 9;
            int i00, i01, i10, i11;
            calc_coords(h, px, kk / 3, kk % 3, dyN, dxN, i00, i01, i10, i11,
                        u00, u01, u10, u11);
            const _Float16* xg = xbase + g * 32;
            q00 = *(const uint4*)(xg + (long)i00 * 256);
            q01 = *(const uint4*)(xg + (long)i01 * 256);
            q10 = *(const uint4*)(xg + (long)i10 * 256);
            q11 = *(const uint4*)(xg + (long)i11 * 256);
            const _Float16* ws = wt3 + (long)sn * 8192 + (long)half * 4096;
            p0 = *(const uint4*)(ws + bn * 32 + bp * 8);
            p1 = *(const uint4*)(ws + (bn + 64) * 32 + bp * 8);
            int s2 = min(sn + 1, 71);
            dyN = cbase[(s2 * 2) * HW + px]; dxN = cbase[(s2 * 2 + 1) * HW + px];
        }
        __syncthreads();

        // ---- MFMA: 2 M-tiles x 4 N-tiles per wave ----
        const int k0 = (lane >> 4) * 8;
        half8 a0 = *(const half8*)&Ald[mh * 32 + (lane & 15)][k0];
        half8 a1 = *(const half8*)&Ald[mh * 32 + 16 + (lane & 15)][k0];
        #pragma unroll
        for (int j = 0; j < 4; ++j) {
            half8 bf = *(const half8*)&Bld[(nh * 4 + j) * 16 + (lane & 15)][k0];
            acc[0][j] = __builtin_amdgcn_mfma_f32_16x16x32_f16(a0, bf, acc[0][j], 0, 0, 0);
            acc[1][j] = __builtin_amdgcn_mfma_f32_16x16x32_f16(a1, bf, acc[1][j], 0, 0, 0);
        }
        __syncthreads();
    }

    // ---- epilogue ----
    #pragma unroll
    for (int mi = 0; mi < 2; ++mi) {
        int px0 = mh * 32 + mi * 16 + (lane >> 4) * 4;
        #pragma unroll
        for (int j = 0; j < 4; ++j) {
            int oc = half * 128 + (nh * 4 + j) * 16 + (lane & 15);
            float bb = b_out[oc];
            float4 v = make_float4(acc[mi][j][0] + bb, acc[mi][j][1] + bb,
                                   acc[mi][j][2] + bb, acc[mi][j][3] + bb);
            *(float4*)&out[((long)b * OO + oc) * HW + h * WW + px0] = v;
        }
    }
}

// ---------------------------------------------------------------------------
extern "C" void kernel_launch(void* const* d_in, const int* in_sizes, int n_in,
                              void* d_out, int out_size, void* d_ws, size_t ws_size,
                              hipStream_t stream) {
    const float* x      = (const float*)d_in[0];
    const float* w_off  = (const float*)d_in[1];
    const float* b_off  = (const float*)d_in[2];
    const float* w_attn = (const float*)d_in[3];
    const float* b_attn = (const float*)d_in[4];
    const float* w_out  = (const float*)d_in[5];
    const float* b_out  = (const float*)d_in[6];
    float* out = (float*)d_out;

    _Float16* x_h     = (_Float16*)d_ws;                    // 8,388,608 halves
    float* conv_buf   = (float*)(x_h + 8388608);            // 7,077,888 floats
    _Float16* wt3     = (_Float16*)(conv_buf + 7077888);    // 589,824 halves
    _Float16* wt_conv = wt3 + 589824;                       // 516,096 halves
    float* bias_c     = (float*)(wt_conv + 516096);         // 224 floats

    repack_w<<<dim3((589824 + 255) / 256), dim3(256), 0, stream>>>(w_out, wt3);
    repack_conv<<<dim3((9 * NPAD * 256 + 255) / 256), dim3(256), 0, stream>>>(
        w_off, b_off, w_attn, b_attn, wt_conv, bias_c);
    repack_x<<<dim3(512), dim3(256), 0, stream>>>(x, x_h);

    conv_mfma<<<dim3(1024), dim3(256), 0, stream>>>(x_h, wt_conv, bias_c, conv_buf);

    sample_gemm_mfma<<<dim3(1024), dim3(256), 0, stream>>>(
        x_h, conv_buf, wt3, b_out, out);
}